// Round 2
// baseline (975.284 us; speedup 1.0000x reference)
//
#include <hip/hip_runtime.h>
#include <cstdint>
#include <cstddef>

typedef unsigned short u16;
typedef __attribute__((ext_vector_type(8))) short short8;
typedef __attribute__((ext_vector_type(4))) float f32x4;

#define T_SEQ 8192
#define NH 16
#define HD 128
#define NCH 64
#define KDIM 2048

constexpr float EPS = 1e-5f;
constexpr float SCALE = 0.08838834764831845f;   // 128^-0.5
constexpr float ROPE_BASE = 600000.0f;

__device__ __forceinline__ u16 f2bf(float f) {
  union { float f; unsigned u; } v; v.f = f;
  unsigned r = v.u + 0x7fffu + ((v.u >> 16) & 1u);
  return (u16)(r >> 16);
}
__device__ __forceinline__ float bf2f(u16 h) {
  union { unsigned u; float f; } v; v.u = ((unsigned)h) << 16;
  return v.f;
}
__device__ __forceinline__ f32x4 mfma16(short8 a, short8 b, f32x4 c) {
  return __builtin_amdgcn_mfma_f32_16x16x32_bf16(a, b, c, 0, 0, 0);
}

// ---------------- weight transpose+cast: W [K][N] fp32 -> Wt [N][K] bf16 ----
__global__ __launch_bounds__(256) void transpose_cast(const float* __restrict__ W,
                                                      u16* __restrict__ Wt, int K, int N) {
  __shared__ u16 tile[64][72];
  int n0 = blockIdx.x * 64, k0 = blockIdx.y * 64;
  int tx = threadIdx.x, ty = threadIdx.y; // (64,4)
  for (int r = ty; r < 64; r += 4)
    tile[r][tx] = f2bf(W[(size_t)(k0 + r) * N + n0 + tx]);
  __syncthreads();
  for (int r = ty; r < 64; r += 4)
    Wt[(size_t)(n0 + r) * K + k0 + tx] = tile[tx][r];
}

// ---------------- main GEMM: C = epi(A @ Bt^T) ----------------
// A [8192][2048] (fp32 if AF32 else bf16), Bt [N][2048] bf16.
// 128x128 tile, BK=32, 4 waves 2x2.
// EPI 0: fp32 out. EPI 1: bf16 out. EPI 2: silu -> scatter into q_t/k_t/v_t.
template <int EPI, int AF32>
__global__ __launch_bounds__(256) void gemm_k(const void* __restrict__ Aptr,
                                              const u16* __restrict__ Bt, int N,
                                              float* __restrict__ Cf,
                                              u16* __restrict__ Cb,
                                              u16* __restrict__ q_t,
                                              u16* __restrict__ k_t,
                                              u16* __restrict__ v_t) {
  __shared__ u16 lA[128 * 40];
  __shared__ u16 lB[128 * 40];
  const int tid = threadIdx.x;
  const int bm = blockIdx.y, bn = blockIdx.x;
  const int wave = tid >> 6, lane = tid & 63;
  const int wm = (wave >> 1) * 64, wn = (wave & 1) * 64;
  const int lr = lane & 15, lg = lane >> 4;
  const int sr = tid >> 2;           // 0..63
  const int sc = (tid & 3) * 8;      // 0,8,16,24
  const size_t arow0 = (size_t)bm * 128;
  const size_t brow0 = (size_t)bn * 128;

  f32x4 acc[4][4];
  #pragma unroll
  for (int i = 0; i < 4; i++)
    #pragma unroll
    for (int j = 0; j < 4; j++) acc[i][j] = (f32x4){0.f, 0.f, 0.f, 0.f};

  for (int k0 = 0; k0 < KDIM; k0 += 32) {
    int4 va0, va1;
    if (AF32) {
      const float* A = (const float*)Aptr;
      const float* a0 = A + (arow0 + sr) * KDIM + k0 + sc;
      const float* a1 = A + (arow0 + sr + 64) * KDIM + k0 + sc;
      float4 x0 = *(const float4*)a0, x1 = *(const float4*)(a0 + 4);
      float4 y0 = *(const float4*)a1, y1 = *(const float4*)(a1 + 4);
      alignas(16) u16 u0[8] = {f2bf(x0.x), f2bf(x0.y), f2bf(x0.z), f2bf(x0.w),
                               f2bf(x1.x), f2bf(x1.y), f2bf(x1.z), f2bf(x1.w)};
      alignas(16) u16 u1[8] = {f2bf(y0.x), f2bf(y0.y), f2bf(y0.z), f2bf(y0.w),
                               f2bf(y1.x), f2bf(y1.y), f2bf(y1.z), f2bf(y1.w)};
      va0 = *(const int4*)u0;
      va1 = *(const int4*)u1;
    } else {
      const u16* A = (const u16*)Aptr;
      va0 = *(const int4*)(A + (arow0 + sr) * KDIM + k0 + sc);
      va1 = *(const int4*)(A + (arow0 + sr + 64) * KDIM + k0 + sc);
    }
    const int4 vb0 = *(const int4*)(Bt + (brow0 + sr) * KDIM + k0 + sc);
    const int4 vb1 = *(const int4*)(Bt + (brow0 + sr + 64) * KDIM + k0 + sc);
    __syncthreads();
    *(int4*)&lA[sr * 40 + sc] = va0;
    *(int4*)&lA[(sr + 64) * 40 + sc] = va1;
    *(int4*)&lB[sr * 40 + sc] = vb0;
    *(int4*)&lB[(sr + 64) * 40 + sc] = vb1;
    __syncthreads();
    short8 af[4], bfr[4];
    #pragma unroll
    for (int i = 0; i < 4; i++)
      af[i] = *(const short8*)&lA[(wm + i * 16 + lr) * 40 + lg * 8];
    #pragma unroll
    for (int j = 0; j < 4; j++)
      bfr[j] = *(const short8*)&lB[(wn + j * 16 + lr) * 40 + lg * 8];
    #pragma unroll
    for (int i = 0; i < 4; i++)
      #pragma unroll
      for (int j = 0; j < 4; j++)
        acc[i][j] = mfma16(af[i], bfr[j], acc[i][j]);
  }

  #pragma unroll
  for (int i = 0; i < 4; i++)
    #pragma unroll
    for (int j = 0; j < 4; j++)
      #pragma unroll
      for (int r = 0; r < 4; r++) {
        int row = bm * 128 + wm + i * 16 + lg * 4 + r;
        int col = bn * 128 + wn + j * 16 + lr;
        float v = acc[i][j][r];
        if (EPI == 0) {
          Cf[(size_t)row * N + col] = v;
        } else if (EPI == 1) {
          Cb[(size_t)row * N + col] = f2bf(v);
        } else {
          float s = v / (1.0f + __expf(-v));   // silu
          int part = col >> 11;
          int h = (col >> 7) & 15;
          int d = col & 127;
          u16* dst = part == 0 ? q_t : (part == 1 ? k_t : v_t);
          dst[((size_t)h * T_SEQ + row) * HD + d] = f2bf(s);
        }
      }
}

// ---------------- per-(t,h) RMSNorm + RoPE, in place on q_t/k_t ----------------
__global__ __launch_bounds__(128) void qk_prep(u16* __restrict__ q_t, u16* __restrict__ k_t,
                                               const int* __restrict__ positions,
                                               const float* __restrict__ q_ln_w,
                                               const float* __restrict__ k_ln_w) {
  const int t = blockIdx.x, h = blockIdx.y, d = threadIdx.x;
  const size_t base = ((size_t)h * T_SEQ + t) * HD + d;
  float qv = bf2f(q_t[base]), kv = bf2f(k_t[base]);
  float s1 = qv * qv, s2 = kv * kv;
  #pragma unroll
  for (int off = 32; off > 0; off >>= 1) {
    s1 += __shfl_xor(s1, off);
    s2 += __shfl_xor(s2, off);
  }
  __shared__ float sh[4];
  if ((d & 63) == 0) { sh[(d >> 6) * 2] = s1; sh[(d >> 6) * 2 + 1] = s2; }
  __syncthreads();
  s1 = sh[0] + sh[2];
  s2 = sh[1] + sh[3];
  float rq = rsqrtf(s1 * (1.0f / 128.0f) + EPS);
  float rk = rsqrtf(s2 * (1.0f / 128.0f) + EPS);
  float qn = qv * rq * q_ln_w[d];
  float kn = kv * rk * k_ln_w[d];
  __shared__ float qsh[128], ksh[128];
  qsh[d] = qn; ksh[d] = kn;
  __syncthreads();
  int i = d & 63;
  float invf = powf(ROPE_BASE, -(float)i * (1.0f / 64.0f));
  float ang = (float)positions[t] * invf;
  float cv = cosf(ang), sv = sinf(ang);
  float q2 = qsh[d ^ 64], k2 = ksh[d ^ 64];
  float qr = (d < 64) ? (qn * cv - q2 * sv) : (qn * cv + q2 * sv);
  float kr = (d < 64) ? (kn * cv - k2 * sv) : (kn * cv + k2 * sv);
  q_t[base] = f2bf(qr * SCALE);
  k_t[base] = f2bf(kr);
}

// ---------------- phase B: G[h][c][e][d] = sum_{t in chunk} V[t][e] K[t][d] ----
// k_t, v_t are [h][t][128]; transpose chunk tiles in LDS (64-t halves).
__global__ __launch_bounds__(256) void attn_phaseB(const u16* __restrict__ k_t,
                                                   const u16* __restrict__ v_t,
                                                   u16* __restrict__ G) {
  const int c = blockIdx.x, h = blockIdx.y;
  __shared__ u16 lV[128 * 72];
  __shared__ u16 lK[128 * 72];
  const int tid = threadIdx.x, wave = tid >> 6, lane = tid & 63;
  const int wm = (wave >> 1) * 64, wn = (wave & 1) * 64;
  const int lr = lane & 15, lg = lane >> 4;
  f32x4 acc[4][4];
  #pragma unroll
  for (int i = 0; i < 4; i++)
    #pragma unroll
    for (int j = 0; j < 4; j++) acc[i][j] = (f32x4){0.f, 0.f, 0.f, 0.f};

  const int tr = tid >> 2, seg = (tid & 3) * 32;   // stage: 4 thr/row, 64 rows
  for (int h2 = 0; h2 < 2; h2++) {
    __syncthreads();
    const u16* vsrc = v_t + ((size_t)h * T_SEQ + c * 128 + h2 * 64 + tr) * HD + seg;
    const u16* ksrc = k_t + ((size_t)h * T_SEQ + c * 128 + h2 * 64 + tr) * HD + seg;
    #pragma unroll
    for (int m = 0; m < 32; m += 8) {
      int4 rv = *(const int4*)(vsrc + m);
      int4 rk = *(const int4*)(ksrc + m);
      const u16* ev = (const u16*)&rv;
      const u16* ek = (const u16*)&rk;
      #pragma unroll
      for (int j = 0; j < 8; j++) {
        lV[(seg + m + j) * 72 + tr] = ev[j];
        lK[(seg + m + j) * 72 + tr] = ek[j];
      }
    }
    __syncthreads();
    #pragma unroll
    for (int kk = 0; kk < 64; kk += 32) {
      short8 af[4], bfr[4];
      #pragma unroll
      for (int i = 0; i < 4; i++)
        af[i] = *(const short8*)&lV[(wm + i * 16 + lr) * 72 + kk + lg * 8];
      #pragma unroll
      for (int j = 0; j < 4; j++)
        bfr[j] = *(const short8*)&lK[(wn + j * 16 + lr) * 72 + kk + lg * 8];
      #pragma unroll
      for (int i = 0; i < 4; i++)
        #pragma unroll
        for (int j = 0; j < 4; j++)
          acc[i][j] = mfma16(af[i], bfr[j], acc[i][j]);
    }
  }
  u16* Gp = G + ((size_t)h * NCH + c) * 16384;
  #pragma unroll
  for (int i = 0; i < 4; i++)
    #pragma unroll
    for (int j = 0; j < 4; j++)
      #pragma unroll
      for (int r = 0; r < 4; r++)
        Gp[(wm + i * 16 + lg * 4 + r) * 128 + wn + j * 16 + lr] = f2bf(acc[i][j][r]);
}

// exclusive prefix over chunk axis, bf16 storage / fp32 accumulator, in place
__global__ __launch_bounds__(256) void prefix_S(u16* __restrict__ G) {
  long idx = (long)blockIdx.x * 256 + threadIdx.x;   // over 16*16384
  int h = (int)(idx >> 14);
  int ed = (int)(idx & 16383);
  float run = 0.f;
  size_t base = (size_t)h * NCH * 16384 + ed;
  for (int c = 0; c < NCH; c++) {
    float g = bf2f(G[base + (size_t)c * 16384]);
    G[base + (size_t)c * 16384] = f2bf(run);
    run += g;
  }
}

// ---------------- phase C: O = tril(Q K^T) V + Q S ----------------
// q_t,k_t [h][t][128] row-major; V transposed in LDS per 64-s half; S bf16 [e][d].
__global__ __launch_bounds__(256) void attn_phaseC(const u16* __restrict__ q_t,
                                                   const u16* __restrict__ k_t,
                                                   const u16* __restrict__ v_t,
                                                   const u16* __restrict__ G,
                                                   u16* __restrict__ o_bf) {
  const int c = blockIdx.x, h = blockIdx.y;
  __shared__ u16 lP[128 * 136];
  __shared__ u16 lV[128 * 72];
  const int tid = threadIdx.x, wave = tid >> 6, lane = tid & 63;
  const int wm = wave * 32;          // 4x1 wave layout, 32 rows each
  const int lr = lane & 15, lg = lane >> 4;

  f32x4 acc1[2][8], acc2[2][8];
  #pragma unroll
  for (int i = 0; i < 2; i++)
    #pragma unroll
    for (int j = 0; j < 8; j++) {
      acc1[i][j] = (f32x4){0.f, 0.f, 0.f, 0.f};
      acc2[i][j] = (f32x4){0.f, 0.f, 0.f, 0.f};
    }

  const u16* Sp = G + ((size_t)h * NCH + c) * 16384;
  const u16* qbase = q_t + ((size_t)h * T_SEQ + c * 128) * HD;
  const u16* kbase = k_t + ((size_t)h * T_SEQ + c * 128) * HD;

  #pragma unroll
  for (int kk = 0; kk < 128; kk += 32) {
    short8 af[2];
    #pragma unroll
    for (int i = 0; i < 2; i++)
      af[i] = *(const short8*)(qbase + (wm + i * 16 + lr) * HD + kk + lg * 8);
    #pragma unroll
    for (int j = 0; j < 8; j++) {
      short8 bK = *(const short8*)(kbase + (j * 16 + lr) * HD + kk + lg * 8);
      short8 bS = *(const short8*)(Sp + (j * 16 + lr) * 128 + kk + lg * 8);
      #pragma unroll
      for (int i = 0; i < 2; i++) {
        acc1[i][j] = mfma16(af[i], bK, acc1[i][j]);   // scores
        acc2[i][j] = mfma16(af[i], bS, acc2[i][j]);   // Q @ S
      }
    }
  }
  // mask scores (tril) and park P in LDS (bf16, row-major over s)
  #pragma unroll
  for (int i = 0; i < 2; i++)
    #pragma unroll
    for (int j = 0; j < 8; j++)
      #pragma unroll
      for (int r = 0; r < 4; r++) {
        int row = wm + i * 16 + lg * 4 + r;
        int col = j * 16 + lr;
        float v = (col <= row) ? acc1[i][j][r] : 0.0f;
        lP[row * 136 + col] = f2bf(v);
      }

  const int tr = tid >> 2, seg = (tid & 3) * 32;
  for (int sh2 = 0; sh2 < 2; sh2++) {
    __syncthreads();
    const u16* vsrc = v_t + ((size_t)h * T_SEQ + c * 128 + sh2 * 64 + tr) * HD + seg;
    #pragma unroll
    for (int m = 0; m < 32; m += 8) {
      int4 rv = *(const int4*)(vsrc + m);
      const u16* ev = (const u16*)&rv;
      #pragma unroll
      for (int j = 0; j < 8; j++) lV[(seg + m + j) * 72 + tr] = ev[j];
    }
    __syncthreads();
    #pragma unroll
    for (int kk = 0; kk < 64; kk += 32) {
      short8 af[2];
      #pragma unroll
      for (int i = 0; i < 2; i++)
        af[i] = *(const short8*)&lP[(wm + i * 16 + lr) * 136 + sh2 * 64 + kk + lg * 8];
      #pragma unroll
      for (int j = 0; j < 8; j++) {
        short8 bV = *(const short8*)&lV[(j * 16 + lr) * 72 + kk + lg * 8];
        #pragma unroll
        for (int i = 0; i < 2; i++)
          acc2[i][j] = mfma16(af[i], bV, acc2[i][j]);
      }
    }
  }
  #pragma unroll
  for (int i = 0; i < 2; i++)
    #pragma unroll
    for (int j = 0; j < 8; j++)
      #pragma unroll
      for (int r = 0; r < 4; r++) {
        int row = wm + i * 16 + lg * 4 + r;
        int e = j * 16 + lr;
        o_bf[(size_t)(c * 128 + row) * 2048 + h * 128 + e] = f2bf(acc2[i][j][r]);
      }
}

// ---------------- gated rmsnorm: gated = sigmoid(gate) * rmsnorm(o) ----------------
__global__ __launch_bounds__(256) void gated_kernel(const u16* __restrict__ o_bf,
                                                    const u16* __restrict__ gate_bf,
                                                    const float* __restrict__ g_norm_w,
                                                    u16* __restrict__ gated_bf) {
  const int t = blockIdx.x, tid = threadIdx.x;
  const u16* orow = o_bf + (size_t)t * 2048;
  float vals[8], ss = 0.f;
  #pragma unroll
  for (int j = 0; j < 8; j++) {
    float v = bf2f(orow[tid + j * 256]);
    vals[j] = v;
    ss += v * v;
  }
  #pragma unroll
  for (int off = 32; off > 0; off >>= 1) ss += __shfl_xor(ss, off);
  __shared__ float sh[4];
  if ((tid & 63) == 0) sh[tid >> 6] = ss;
  __syncthreads();
  ss = sh[0] + sh[1] + sh[2] + sh[3];
  float r = rsqrtf(ss * (1.0f / 2048.0f) + EPS);
  const u16* grow = gate_bf + (size_t)t * 2048;
  u16* drow = gated_bf + (size_t)t * 2048;
  #pragma unroll
  for (int j = 0; j < 8; j++) {
    int col = tid + j * 256;
    float normed = vals[j] * r * g_norm_w[col];
    float g = bf2f(grow[col]);
    float sg = 1.0f / (1.0f + __expf(-g));
    drow[col] = f2bf(normed * sg);
  }
}

// ---------------- launch ----------------
extern "C" void kernel_launch(void* const* d_in, const int* in_sizes, int n_in,
                              void* d_out, int out_size, void* d_ws, size_t ws_size,
                              hipStream_t stream) {
  const float* x = (const float*)d_in[0];
  const int* positions = (const int*)d_in[1];
  const float* Wqkv = (const float*)d_in[2];
  const float* q_ln_w = (const float*)d_in[3];
  const float* k_ln_w = (const float*)d_in[4];
  const float* Wg = (const float*)d_in[5];
  const float* g_norm_w = (const float*)d_in[6];
  const float* Wo = (const float*)d_in[7];
  float* out = (float*)d_out;

  // Workspace layout (bytes). Aliased by lifetime:
  //   slot0 [0, 33.5M):      WqkvT (gemm<2>) -> G bf16 (phaseB..C) -> gate_bf
  //   [33.5M, 41.9M):        WgT (live until late gate gemm)
  //   [41.9M, 75.5M):        q_t  -> gated
  //   [75.5M, 109.1M):       k_t  -> WoT
  //   [109.1M, 142.6M):      v_t
  //   [142.6M, 176.2M):      o_bf
  char* ws = (char*)d_ws;
  const size_t MB32 = (size_t)33554432;
  u16* slot0 = (u16*)ws;
  u16* WqkvT = slot0;
  u16* G     = slot0;
  u16* gate_bf = slot0;
  u16* WgT   = (u16*)(ws + MB32);
  u16* q_t   = (u16*)(ws + MB32 + 8388608);
  u16* gated = q_t;
  u16* k_t   = (u16*)(ws + MB32 + 8388608 + MB32);
  u16* WoT   = k_t;
  u16* v_t   = (u16*)(ws + MB32 + 8388608 + 2 * MB32);
  u16* o_bf  = (u16*)(ws + MB32 + 8388608 + 3 * MB32);
  const size_t needed = MB32 + 8388608 + 4 * MB32;   // 176,160,768
  if (ws_size < needed) return;

  transpose_cast<<<dim3(96, 32), dim3(64, 4), 0, stream>>>(Wqkv, WqkvT, 2048, 6144);
  transpose_cast<<<dim3(32, 32), dim3(64, 4), 0, stream>>>(Wg, WgT, 2048, 2048);

  gemm_k<2, 1><<<dim3(48, 64), 256, 0, stream>>>(x, WqkvT, 6144, nullptr, nullptr, q_t, k_t, v_t);

  qk_prep<<<dim3(8192, 16), 128, 0, stream>>>(q_t, k_t, positions, q_ln_w, k_ln_w);

  attn_phaseB<<<dim3(64, 16), 256, 0, stream>>>(k_t, v_t, G);
  prefix_S<<<1024, 256, 0, stream>>>(G);
  attn_phaseC<<<dim3(64, 16), 256, 0, stream>>>(q_t, k_t, v_t, G, o_bf);

  // slot0 (G) now dead -> reuse for gate
  gemm_k<1, 1><<<dim3(16, 64), 256, 0, stream>>>(x, WgT, 2048, nullptr, gate_bf, nullptr, nullptr, nullptr);
  gated_kernel<<<8192, 256, 0, stream>>>(o_bf, gate_bf, g_norm_w, gated);

  transpose_cast<<<dim3(32, 32), dim3(64, 4), 0, stream>>>(Wo, WoT, 2048, 2048);
  gemm_k<0, 0><<<dim3(16, 64), 256, 0, stream>>>(gated, WoT, 2048, out, nullptr, nullptr, nullptr, nullptr);
}

// Round 3
// 796.027 us; speedup vs baseline: 1.2252x; 1.2252x over previous
//
#include <hip/hip_runtime.h>
#include <cstdint>
#include <cstddef>

typedef unsigned short u16;
typedef __attribute__((ext_vector_type(8))) short short8;
typedef __attribute__((ext_vector_type(4))) float f32x4;

#define T_SEQ 8192
#define NH 16
#define HD 128
#define NCH 64
#define KDIM 2048

constexpr float EPS = 1e-5f;
constexpr float SCALE = 0.08838834764831845f;   // 128^-0.5

__device__ __forceinline__ u16 f2bf(float f) {
  union { float f; unsigned u; } v; v.f = f;
  unsigned r = v.u + 0x7fffu + ((v.u >> 16) & 1u);
  return (u16)(r >> 16);
}
__device__ __forceinline__ float bf2f(u16 h) {
  union { unsigned u; float f; } v; v.u = ((unsigned)h) << 16;
  return v.f;
}
__device__ __forceinline__ f32x4 mfma16(short8 a, short8 b, f32x4 c) {
  return __builtin_amdgcn_mfma_f32_16x16x32_bf16(a, b, c, 0, 0, 0);
}
// async global->LDS, 16B per lane; l must be wave-uniform (lane offset = lane*16B)
__device__ __forceinline__ void gl2lds(const u16* g, u16* l) {
  __builtin_amdgcn_global_load_lds(
      (const __attribute__((address_space(1))) void*)g,
      (__attribute__((address_space(3))) void*)l, 16, 0, 0);
}

// ---------------- fp32 -> bf16 cast ----------------
__global__ __launch_bounds__(256) void cast_f32_bf16(const float* __restrict__ src,
                                                     u16* __restrict__ dst, long n) {
  long i = ((long)blockIdx.x * 256 + threadIdx.x) * 8;
  if (i >= n) return;
  float4 a = *(const float4*)(src + i);
  float4 b = *(const float4*)(src + i + 4);
  alignas(16) u16 u[8] = {f2bf(a.x), f2bf(a.y), f2bf(a.z), f2bf(a.w),
                          f2bf(b.x), f2bf(b.y), f2bf(b.z), f2bf(b.w)};
  *(int4*)(dst + i) = *(const int4*)u;
}

// ---------------- weight transpose+cast: W [K][N] fp32 -> Wt [N][K] bf16 ----
__global__ __launch_bounds__(256) void transpose_cast(const float* __restrict__ W,
                                                      u16* __restrict__ Wt, int K, int N) {
  __shared__ u16 tile[64][72];
  int n0 = blockIdx.x * 64, k0 = blockIdx.y * 64;
  int tx = threadIdx.x, ty = threadIdx.y; // (64,4)
  for (int r = ty; r < 64; r += 4)
    tile[r][tx] = f2bf(W[(size_t)(k0 + r) * N + n0 + tx]);
  __syncthreads();
  for (int r = ty; r < 64; r += 4)
    Wt[(size_t)(n0 + r) * K + k0 + tx] = tile[tx][r];
}

// ---------------- main GEMM: C = epi(A @ Bt^T) ----------------
// A [8192][2048] bf16, Bt [N][2048] bf16. 128x128 tile, BK=32, 4 waves 2x2.
// global_load_lds width=16 staging (m97 structure), unpadded LDS [128][32].
// EPI 0: fp32 out. EPI 1: bf16 out. EPI 2: silu -> scatter into q_t/k_t/v_t.
template <int EPI>
__global__ __launch_bounds__(256) void gemm_k(const u16* __restrict__ A,
                                              const u16* __restrict__ Bt, int N,
                                              float* __restrict__ Cf,
                                              u16* __restrict__ Cb,
                                              u16* __restrict__ q_t,
                                              u16* __restrict__ k_t,
                                              u16* __restrict__ v_t) {
  __shared__ u16 lA[128 * 32];
  __shared__ u16 lB[128 * 32];
  const int tid = threadIdx.x;
  const int bm = blockIdx.y, bn = blockIdx.x;
  const int wave = tid >> 6, lane = tid & 63;
  const int wm = (wave >> 1) * 64, wn = (wave & 1) * 64;
  const int lr = lane & 15, lg = lane >> 4;
  // staging: wave w covers rows [32w,32w+32) of both tiles as two 16-row chunks;
  // lane -> (row = lane/4, col = (lane%4)*8), LDS offset = lane*16B (HW-implied)
  const int srow = wave * 32 + (lane >> 2);
  const int scol = (lane & 3) * 8;
  const u16* gA = A + ((size_t)bm * 128 + srow) * KDIM + scol;
  const u16* gB = Bt + ((size_t)bn * 128 + srow) * KDIM + scol;
  u16* lA0 = &lA[wave * 1024];
  u16* lB0 = &lB[wave * 1024];

  f32x4 acc[4][4];
  #pragma unroll
  for (int i = 0; i < 4; i++)
    #pragma unroll
    for (int j = 0; j < 4; j++) acc[i][j] = (f32x4){0.f, 0.f, 0.f, 0.f};

  for (int k0 = 0; k0 < KDIM; k0 += 32) {
    __syncthreads();                      // prev iter's ds_reads done
    gl2lds(gA + k0, lA0);
    gl2lds(gA + (size_t)16 * KDIM + k0, lA0 + 512);
    gl2lds(gB + k0, lB0);
    gl2lds(gB + (size_t)16 * KDIM + k0, lB0 + 512);
    __syncthreads();                      // drains vmcnt (compiler-inserted)
    short8 af[4], bfr[4];
    #pragma unroll
    for (int i = 0; i < 4; i++)
      af[i] = *(const short8*)&lA[(wm + i * 16 + lr) * 32 + lg * 8];
    #pragma unroll
    for (int j = 0; j < 4; j++)
      bfr[j] = *(const short8*)&lB[(wn + j * 16 + lr) * 32 + lg * 8];
    #pragma unroll
    for (int i = 0; i < 4; i++)
      #pragma unroll
      for (int j = 0; j < 4; j++)
        acc[i][j] = mfma16(af[i], bfr[j], acc[i][j]);
  }

  #pragma unroll
  for (int i = 0; i < 4; i++)
    #pragma unroll
    for (int j = 0; j < 4; j++)
      #pragma unroll
      for (int r = 0; r < 4; r++) {
        int row = bm * 128 + wm + i * 16 + lg * 4 + r;
        int col = bn * 128 + wn + j * 16 + lr;
        float v = acc[i][j][r];
        if (EPI == 0) {
          Cf[(size_t)row * N + col] = v;
        } else if (EPI == 1) {
          Cb[(size_t)row * N + col] = f2bf(v);
        } else {
          float s = v / (1.0f + __expf(-v));   // silu
          int part = col >> 11;
          int h = (col >> 7) & 15;
          int d = col & 127;
          u16* dst = part == 0 ? q_t : (part == 1 ? k_t : v_t);
          dst[((size_t)h * T_SEQ + row) * HD + d] = f2bf(s);
        }
      }
}

// ---------------- per-(t,h) RMSNorm + RoPE, in place on q_t/k_t ----------------
__global__ __launch_bounds__(128) void qk_prep(u16* __restrict__ q_t, u16* __restrict__ k_t,
                                               const int* __restrict__ positions,
                                               const float* __restrict__ q_ln_w,
                                               const float* __restrict__ k_ln_w) {
  const int t = blockIdx.x, h = blockIdx.y, d = threadIdx.x;
  const size_t base = ((size_t)h * T_SEQ + t) * HD + d;
  float qv = bf2f(q_t[base]), kv = bf2f(k_t[base]);
  float s1 = qv * qv, s2 = kv * kv;
  #pragma unroll
  for (int off = 32; off > 0; off >>= 1) {
    s1 += __shfl_xor(s1, off);
    s2 += __shfl_xor(s2, off);
  }
  __shared__ float sh[4];
  if ((d & 63) == 0) { sh[(d >> 6) * 2] = s1; sh[(d >> 6) * 2 + 1] = s2; }
  __syncthreads();
  s1 = sh[0] + sh[2];
  s2 = sh[1] + sh[3];
  float rq = rsqrtf(s1 * (1.0f / 128.0f) + EPS);
  float rk = rsqrtf(s2 * (1.0f / 128.0f) + EPS);
  float qn = qv * rq * q_ln_w[d];
  float kn = kv * rk * k_ln_w[d];
  __shared__ float qsh[128], ksh[128];
  qsh[d] = qn; ksh[d] = kn;
  __syncthreads();
  int i = d & 63;
  // 1/ROPE_BASE^(i/64) = 2^(-i*log2(6e5)/64); log2(600000)=19.194593
  float invf = exp2f((float)i * (-19.194593f / 64.0f));
  float ang = (float)positions[t] * invf;
  float cv = cosf(ang), sv = sinf(ang);
  float q2 = qsh[d ^ 64], k2 = ksh[d ^ 64];
  float qr = (d < 64) ? (qn * cv - q2 * sv) : (qn * cv + q2 * sv);
  float kr = (d < 64) ? (kn * cv - k2 * sv) : (kn * cv + k2 * sv);
  q_t[base] = f2bf(qr * SCALE);
  k_t[base] = f2bf(kr);
}

// ---------------- phase B: G[h][c][e][d] = sum_{t in chunk} V[t][e] K[t][d] ----
__global__ __launch_bounds__(256) void attn_phaseB(const u16* __restrict__ k_t,
                                                   const u16* __restrict__ v_t,
                                                   u16* __restrict__ G) {
  const int c = blockIdx.x, h = blockIdx.y;
  __shared__ u16 lV[128 * 72];
  __shared__ u16 lK[128 * 72];
  const int tid = threadIdx.x, wave = tid >> 6, lane = tid & 63;
  const int wm = (wave >> 1) * 64, wn = (wave & 1) * 64;
  const int lr = lane & 15, lg = lane >> 4;
  f32x4 acc[4][4];
  #pragma unroll
  for (int i = 0; i < 4; i++)
    #pragma unroll
    for (int j = 0; j < 4; j++) acc[i][j] = (f32x4){0.f, 0.f, 0.f, 0.f};

  const int tr = tid >> 2, seg = (tid & 3) * 32;   // stage: 4 thr/row, 64 rows
  for (int h2 = 0; h2 < 2; h2++) {
    __syncthreads();
    const u16* vsrc = v_t + ((size_t)h * T_SEQ + c * 128 + h2 * 64 + tr) * HD + seg;
    const u16* ksrc = k_t + ((size_t)h * T_SEQ + c * 128 + h2 * 64 + tr) * HD + seg;
    #pragma unroll
    for (int m = 0; m < 32; m += 8) {
      int4 rv = *(const int4*)(vsrc + m);
      int4 rk = *(const int4*)(ksrc + m);
      const u16* ev = (const u16*)&rv;
      const u16* ek = (const u16*)&rk;
      #pragma unroll
      for (int j = 0; j < 8; j++) {
        lV[(seg + m + j) * 72 + tr] = ev[j];
        lK[(seg + m + j) * 72 + tr] = ek[j];
      }
    }
    __syncthreads();
    #pragma unroll
    for (int kk = 0; kk < 64; kk += 32) {
      short8 af[4], bfr[4];
      #pragma unroll
      for (int i = 0; i < 4; i++)
        af[i] = *(const short8*)&lV[(wm + i * 16 + lr) * 72 + kk + lg * 8];
      #pragma unroll
      for (int j = 0; j < 4; j++)
        bfr[j] = *(const short8*)&lK[(wn + j * 16 + lr) * 72 + kk + lg * 8];
      #pragma unroll
      for (int i = 0; i < 4; i++)
        #pragma unroll
        for (int j = 0; j < 4; j++)
          acc[i][j] = mfma16(af[i], bfr[j], acc[i][j]);
    }
  }
  u16* Gp = G + ((size_t)h * NCH + c) * 16384;
  #pragma unroll
  for (int i = 0; i < 4; i++)
    #pragma unroll
    for (int j = 0; j < 4; j++)
      #pragma unroll
      for (int r = 0; r < 4; r++)
        Gp[(wm + i * 16 + lg * 4 + r) * 128 + wn + j * 16 + lr] = f2bf(acc[i][j][r]);
}

// exclusive prefix over chunk axis, bf16 storage / fp32 accumulator, in place
__global__ __launch_bounds__(256) void prefix_S(u16* __restrict__ G) {
  long idx = (long)blockIdx.x * 256 + threadIdx.x;   // over 16*16384
  int h = (int)(idx >> 14);
  int ed = (int)(idx & 16383);
  float run = 0.f;
  size_t base = (size_t)h * NCH * 16384 + ed;
  for (int c = 0; c < NCH; c++) {
    float g = bf2f(G[base + (size_t)c * 16384]);
    G[base + (size_t)c * 16384] = f2bf(run);
    run += g;
  }
}

// ---------------- phase C: O = tril(Q K^T) V + Q S ----------------
__global__ __launch_bounds__(256) void attn_phaseC(const u16* __restrict__ q_t,
                                                   const u16* __restrict__ k_t,
                                                   const u16* __restrict__ v_t,
                                                   const u16* __restrict__ G,
                                                   u16* __restrict__ o_bf) {
  const int c = blockIdx.x, h = blockIdx.y;
  __shared__ u16 lP[128 * 136];
  __shared__ u16 lV[128 * 72];
  const int tid = threadIdx.x, wave = tid >> 6, lane = tid & 63;
  const int wm = wave * 32;          // 4x1 wave layout, 32 rows each
  const int lr = lane & 15, lg = lane >> 4;

  f32x4 acc1[2][8], acc2[2][8];
  #pragma unroll
  for (int i = 0; i < 2; i++)
    #pragma unroll
    for (int j = 0; j < 8; j++) {
      acc1[i][j] = (f32x4){0.f, 0.f, 0.f, 0.f};
      acc2[i][j] = (f32x4){0.f, 0.f, 0.f, 0.f};
    }

  const u16* Sp = G + ((size_t)h * NCH + c) * 16384;
  const u16* qbase = q_t + ((size_t)h * T_SEQ + c * 128) * HD;
  const u16* kbase = k_t + ((size_t)h * T_SEQ + c * 128) * HD;

  #pragma unroll
  for (int kk = 0; kk < 128; kk += 32) {
    short8 af[2];
    #pragma unroll
    for (int i = 0; i < 2; i++)
      af[i] = *(const short8*)(qbase + (wm + i * 16 + lr) * HD + kk + lg * 8);
    #pragma unroll
    for (int j = 0; j < 8; j++) {
      short8 bK = *(const short8*)(kbase + (j * 16 + lr) * HD + kk + lg * 8);
      short8 bS = *(const short8*)(Sp + (j * 16 + lr) * 128 + kk + lg * 8);
      #pragma unroll
      for (int i = 0; i < 2; i++) {
        acc1[i][j] = mfma16(af[i], bK, acc1[i][j]);   // scores
        acc2[i][j] = mfma16(af[i], bS, acc2[i][j]);   // Q @ S
      }
    }
  }
  // mask scores (tril) and park P in LDS (bf16, row-major over s)
  #pragma unroll
  for (int i = 0; i < 2; i++)
    #pragma unroll
    for (int j = 0; j < 8; j++)
      #pragma unroll
      for (int r = 0; r < 4; r++) {
        int row = wm + i * 16 + lg * 4 + r;
        int col = j * 16 + lr;
        float v = (col <= row) ? acc1[i][j][r] : 0.0f;
        lP[row * 136 + col] = f2bf(v);
      }

  const int tr = tid >> 2, seg = (tid & 3) * 32;
  for (int sh2 = 0; sh2 < 2; sh2++) {
    __syncthreads();
    const u16* vsrc = v_t + ((size_t)h * T_SEQ + c * 128 + sh2 * 64 + tr) * HD + seg;
    #pragma unroll
    for (int m = 0; m < 32; m += 8) {
      int4 rv = *(const int4*)(vsrc + m);
      const u16* ev = (const u16*)&rv;
      #pragma unroll
      for (int j = 0; j < 8; j++) lV[(seg + m + j) * 72 + tr] = ev[j];
    }
    __syncthreads();
    #pragma unroll
    for (int kk = 0; kk < 64; kk += 32) {
      short8 af[2];
      #pragma unroll
      for (int i = 0; i < 2; i++)
        af[i] = *(const short8*)&lP[(wm + i * 16 + lr) * 136 + sh2 * 64 + kk + lg * 8];
      #pragma unroll
      for (int j = 0; j < 8; j++) {
        short8 bV = *(const short8*)&lV[(j * 16 + lr) * 72 + kk + lg * 8];
        #pragma unroll
        for (int i = 0; i < 2; i++)
          acc2[i][j] = mfma16(af[i], bV, acc2[i][j]);
      }
    }
  }
  #pragma unroll
  for (int i = 0; i < 2; i++)
    #pragma unroll
    for (int j = 0; j < 8; j++)
      #pragma unroll
      for (int r = 0; r < 4; r++) {
        int row = wm + i * 16 + lg * 4 + r;
        int e = j * 16 + lr;
        o_bf[(size_t)(c * 128 + row) * 2048 + h * 128 + e] = f2bf(acc2[i][j][r]);
      }
}

// ---------------- gated rmsnorm: gated = sigmoid(gate) * rmsnorm(o) ----------------
__global__ __launch_bounds__(256) void gated_kernel(const u16* __restrict__ o_bf,
                                                    const u16* __restrict__ gate_bf,
                                                    const float* __restrict__ g_norm_w,
                                                    u16* __restrict__ gated_bf) {
  const int t = blockIdx.x, tid = threadIdx.x;
  const u16* orow = o_bf + (size_t)t * 2048;
  float vals[8], ss = 0.f;
  #pragma unroll
  for (int j = 0; j < 8; j++) {
    float v = bf2f(orow[tid + j * 256]);
    vals[j] = v;
    ss += v * v;
  }
  #pragma unroll
  for (int off = 32; off > 0; off >>= 1) ss += __shfl_xor(ss, off);
  __shared__ float sh[4];
  if ((tid & 63) == 0) sh[tid >> 6] = ss;
  __syncthreads();
  ss = sh[0] + sh[1] + sh[2] + sh[3];
  float r = rsqrtf(ss * (1.0f / 2048.0f) + EPS);
  const u16* grow = gate_bf + (size_t)t * 2048;
  u16* drow = gated_bf + (size_t)t * 2048;
  #pragma unroll
  for (int j = 0; j < 8; j++) {
    int col = tid + j * 256;
    float normed = vals[j] * r * g_norm_w[col];
    float g = bf2f(grow[col]);
    float sg = 1.0f / (1.0f + __expf(-g));
    drow[col] = f2bf(normed * sg);
  }
}

// ---------------- launch ----------------
extern "C" void kernel_launch(void* const* d_in, const int* in_sizes, int n_in,
                              void* d_out, int out_size, void* d_ws, size_t ws_size,
                              hipStream_t stream) {
  const float* x = (const float*)d_in[0];
  const int* positions = (const int*)d_in[1];
  const float* Wqkv = (const float*)d_in[2];
  const float* q_ln_w = (const float*)d_in[3];
  const float* k_ln_w = (const float*)d_in[4];
  const float* Wg = (const float*)d_in[5];
  const float* g_norm_w = (const float*)d_in[6];
  const float* Wo = (const float*)d_in[7];
  float* out = (float*)d_out;

  // Regions (32 MiB each unless noted), aliased by lifetime:
  //  R0 [0,32M):      WqkvT(25.2M) -> G -> gate_bf
  //  R1 [32M,40M):    WgT (8M)
  //  R2 [40M,72M):    q_t -> x_bf2 -> gated
  //  R3 [72M,104M):   k_t -> WoT
  //  R4 [104M,136M):  v_t
  //  R5 [136M,168M):  x_bf -> o_bf
  char* ws = (char*)d_ws;
  const size_t M32 = (size_t)32 * 1024 * 1024;
  u16* WqkvT   = (u16*)ws;
  u16* G       = (u16*)ws;
  u16* gate_bf = (u16*)ws;
  u16* WgT     = (u16*)(ws + M32);
  u16* q_t     = (u16*)(ws + M32 + 8388608);
  u16* x_bf2   = q_t;
  u16* gated   = q_t;
  u16* k_t     = (u16*)(ws + M32 + 8388608 + M32);
  u16* WoT     = k_t;
  u16* v_t     = (u16*)(ws + M32 + 8388608 + 2 * M32);
  u16* x_bf    = (u16*)(ws + M32 + 8388608 + 3 * M32);
  u16* o_bf    = x_bf;
  const size_t needed = M32 + 8388608 + 4 * M32;   // 176,160,768
  if (ws_size < needed) return;

  cast_f32_bf16<<<8192, 256, 0, stream>>>(x, x_bf, (long)8192 * 2048);
  transpose_cast<<<dim3(96, 32), dim3(64, 4), 0, stream>>>(Wqkv, WqkvT, 2048, 6144);
  transpose_cast<<<dim3(32, 32), dim3(64, 4), 0, stream>>>(Wg, WgT, 2048, 2048);

  gemm_k<2><<<dim3(48, 64), 256, 0, stream>>>(x_bf, WqkvT, 6144, nullptr, nullptr, q_t, k_t, v_t);

  qk_prep<<<dim3(8192, 16), 128, 0, stream>>>(q_t, k_t, positions, q_ln_w, k_ln_w);

  attn_phaseB<<<dim3(64, 16), 256, 0, stream>>>(k_t, v_t, G);
  prefix_S<<<1024, 256, 0, stream>>>(G);
  attn_phaseC<<<dim3(64, 16), 256, 0, stream>>>(q_t, k_t, v_t, G, o_bf);

  // q_t dead -> recast x for the gate GEMM; G dead -> gate_bf
  cast_f32_bf16<<<8192, 256, 0, stream>>>(x, x_bf2, (long)8192 * 2048);
  gemm_k<1><<<dim3(16, 64), 256, 0, stream>>>(x_bf2, WgT, 2048, nullptr, gate_bf, nullptr, nullptr, nullptr);
  gated_kernel<<<8192, 256, 0, stream>>>(o_bf, gate_bf, g_norm_w, gated);

  transpose_cast<<<dim3(32, 32), dim3(64, 4), 0, stream>>>(Wo, WoT, 2048, 2048);
  gemm_k<0><<<dim3(16, 64), 256, 0, stream>>>(gated, WoT, 2048, out, nullptr, nullptr, nullptr, nullptr);
}